// Round 1
// 260.193 us; speedup vs baseline: 1.1019x; 1.1019x over previous
//
#include <hip/hip_runtime.h>
#include <hip/hip_bf16.h>
#include <math.h>

// QRNN3D fused via bf16 MFMA implicit conv-GEMM + in-register fo-pool.
// GEMM per (b,h,t): D[32 gate-ch][128 pix] = sum over 27 taps of
//   A(tap)[32ch x 16c] * B(tap)[16c x 128pix],  A = weights in VGPRs (t-invariant),
//   B = im2col x-slice in LDS ([wpos][c] c-minor, XOR-swizzled, zero-padded borders).
// C/D layout (32x32x16): col=lane&31=pixel, row=ch=(reg&3)+8*(reg>>2)+4*(lane>>5)
//   => z-gate ch in acc[r], f-gate ch+16 in acc[r+8], same lane: recurrence is
//   per-lane register math; stores coalesced (lane = pixel).
// LDS: 4-slot ring of t-planes (12480 B each, 49920 total).
//
// THIS REVISION: software-pipelined staging (T14 split). Plane t+2's global
// loads are ISSUED (into 32 regs, dwordx4) right after the barrier of iter t
// and COMMITTED to LDS at the start of iter t+1 — the load latency hides under
// a full compute(t) phase instead of sitting on the critical path between
// stage and barrier. Staging also re-shaped: 192 threads x 8 dwordx4 instead
// of 256 threads x 24 scalar dwords (4x fewer VMEM instructions).
// Slot safety: commit at iter t writes slot (t+1)&3; concurrent compute(t-1)
// regions read slots (t-2,t,t-1)&3 -> the written slot is the disjoint 4th.

namespace {
constexpr int kB = 4, kC = 16, kT = 31, kH = 128, kW = 128, kHid = 16;
constexpr int kHW  = kH * kW;
constexpr int kTHW = kT * kHW;
constexpr int kCS  = 16;            // shorts per wpos (16 c, swizzled, no pad)
constexpr int kRS  = 130 * kCS;     // row stride (shorts) = 2080
constexpr int kPS  = 3 * kRS;       // plane stride (shorts) = 6240 (12480 B)
constexpr int kSlots = 4;
}

typedef __attribute__((ext_vector_type(8)))  short  short8;
typedef __attribute__((ext_vector_type(4)))  float  floatv4;
typedef __attribute__((ext_vector_type(16))) float  floatx16;

__device__ __forceinline__ unsigned short f2bf(float f) {
    __hip_bfloat16 h = __float2bfloat16(f);   // RTN
    return __builtin_bit_cast(unsigned short, h);
}

__global__ __launch_bounds__(256, 2) void qrnn_mfma(
    const float* __restrict__ x, const float* __restrict__ Wt,
    const float* __restrict__ bias, float* __restrict__ out)
{
    __shared__ unsigned short lds[kSlots * kPS];   // 49920 B

    // XCD-aware decode: 64 consecutive h per XCD -> staging rows L2-resident.
    const int id  = blockIdx.x;          // 0..511
    const int bh  = (id & 7) * 64 + (id >> 3);
    const int b   = bh >> 7;
    const int h   = bh & (kH - 1);

    const int tid  = threadIdx.x;
    const int lane = tid & 63;
    const int m    = lane & 31;          // A: gate channel ; B/D: pixel-in-tile
    const int hi   = lane >> 5;
    const int chi  = hi * 8;             // k-octet base (c dimension)
    const int n0   = (tid >> 6) * 32;    // wave's pixel tile base

    const float* xb = x + b * (kC * kTHW);

    // ---- A-operand: all 27 tap fragments of W, bf16, in registers ----
    short8 wf[27];
#pragma unroll
    for (int tap = 0; tap < 27; ++tap) {
        short8 v;
#pragma unroll
        for (int j = 0; j < 8; ++j)
            v[j] = (short)f2bf(Wt[m * (kC * 27) + (chi + j) * 27 + tap]);
        wf[tap] = v;
    }

    // ---- per-lane recurrence state, biases, output offsets ----
    float st[8], zb[8], fbv[8];
    int ooff[8];
    const int P = n0 + m;                // this lane's pixel (w coordinate)
#pragma unroll
    for (int r = 0; r < 8; ++r) {
        const int hid = (r & 3) + 8 * (r >> 2) + 4 * hi;   // D-row for reg r
        zb[r]  = bias[hid];
        fbv[r] = bias[kHid + hid];
        st[r]  = 0.0f;
        ooff[r] = ((b * kHid + hid) * kT) * kHW + h * kW + P;
    }

    // ---- B-operand lane base addresses (XOR swizzle splits kw parity) ----
    unsigned short* bA = lds + P * kCS       + (chi ^ ((P & 1) * 8));       // kw=0 (+64B: kw=2)
    unsigned short* bB = lds + (P + 1) * kCS + (chi ^ (((P + 1) & 1) * 8)); // kw=1

    // ---- pipelined staging: thread = (kh, w-quad, c-octet), 192 active ----
    const bool sact = tid < 192;
    const int  skh  = tid >> 6;          // 0..2 for active threads (wave-uniform)
    const int  swq  = tid & 31;          // w-quad: covers w = swq*4 .. swq*4+3
    const int  soct = (tid >> 5) & 1;    // c-octet 0 or 8
    const int  shr  = h + skh - 1;       // global row this thread stages
    const bool srow = sact && (shr >= 0) && (shr < kH);   // wave-uniform
    const float* sbase = xb + (soct * 8) * kTHW + shr * kW + swq * 4;
    unsigned short* cb0 = lds + skh * kRS + (swq * 4 + 1) * kCS;  // + slot*kPS + q*kCS + swz

    floatv4 sv[8];                       // staged plane: c = soct*8+j, w = quad lane q

    auto sissue = [&](int tp) {          // issue global loads for plane tp (no wait)
#pragma unroll
        for (int j = 0; j < 8; ++j) sv[j] = floatv4{0.f, 0.f, 0.f, 0.f};
        if (srow && (unsigned)tp < (unsigned)kT) {    // wave-uniform branch
            const float* s = sbase + tp * kHW;
#pragma unroll
            for (int j = 0; j < 8; ++j)
                sv[j] = *(const floatv4*)(s + j * kTHW);
        }
    };
    auto scommit = [&](int tp) {         // cvt + write plane tp into its ring slot
        if (sact) {
            unsigned short* pl = cb0 + ((tp + 2 * kSlots) & (kSlots - 1)) * kPS;
#pragma unroll
            for (int q = 0; q < 4; ++q) {
                // wp = swq*4 + q + 1 -> parity = (q+1)&1 ; XOR bank swizzle
                const int sw = (soct * 8) ^ ((((q + 1) & 1)) * 8);
                short8 v;
#pragma unroll
                for (int j = 0; j < 8; ++j) v[j] = (short)f2bf(sv[j][q]);
                *(short8*)(pl + q * kCS + sw) = v;
            }
        }
    };

    // ---- halo columns (wpos 0 and 129) of all slots: zero once, never rewritten ----
    if (tid < 48) {
        const int s = tid / 12, rem = tid % 12;
        const int row = rem >> 2, q = rem & 3;
        const int wp = (q & 1) * 129;
        const int c0 = (q >> 1) * 8;
        const short8 z = {0, 0, 0, 0, 0, 0, 0, 0};
        *(short8*)(lds + s * kPS + row * kRS + wp * kCS + (c0 ^ ((wp & 1) * 8))) = z;
    }

    // ---- prologue: plane -1 (zeros) -> slot 3, plane 0 -> slot 0, plane 1 in regs ----
    sissue(-1); scommit(-1);
    sissue(0);  scommit(0);
    sissue(1);

    for (int t = 0; t < kT; ++t) {
        scommit(t + 1);                  // loads issued a full iteration ago
        __syncthreads();
        sissue(t + 2);                   // in flight across compute(t) + epilogue

        floatx16 acc = {0,0,0,0,0,0,0,0,0,0,0,0,0,0,0,0};
#pragma unroll
        for (int kd = 0; kd < 3; ++kd) {
            const int soff = ((t + kd + 2 * kSlots - 1) & (kSlots - 1)) * kPS;
#pragma unroll
            for (int kh = 0; kh < 3; ++kh) {
                const int o = soff + kh * kRS;
                const short8 b0 = *(const short8*)(bA + o);        // kw=0 -> x[P-1]
                const short8 b1 = *(const short8*)(bB + o);        // kw=1 -> x[P]
                const short8 b2 = *(const short8*)(bA + o + 2 * kCS); // kw=2 -> x[P+1]
                acc = __builtin_amdgcn_mfma_f32_32x32x16_bf16(wf[kd*9 + kh*3 + 0], b0, acc, 0, 0, 0);
                acc = __builtin_amdgcn_mfma_f32_32x32x16_bf16(wf[kd*9 + kh*3 + 1], b1, acc, 0, 0, 0);
                acc = __builtin_amdgcn_mfma_f32_32x32x16_bf16(wf[kd*9 + kh*3 + 2], b2, acc, 0, 0, 0);
            }
        }

        // epilogue: gates -> activations -> fo-pool -> coalesced store
#pragma unroll
        for (int r = 0; r < 8; ++r) {
            const float zp = acc[r]     + zb[r];
            const float fp = acc[r + 8] + fbv[r];
            const float e2 = __expf(2.0f * zp);
            const float z  = 1.0f - 2.0f * __builtin_amdgcn_rcpf(e2 + 1.0f);  // tanh(zp)
            const float f  = __builtin_amdgcn_rcpf(1.0f + __expf(-fp));       // sigmoid(fp)
            st[r] = z + f * (st[r] - z);
            out[ooff[r] + t * kHW] = st[r];
        }
    }
}

extern "C" void kernel_launch(void* const* d_in, const int* in_sizes, int n_in,
                              void* d_out, int out_size, void* d_ws, size_t ws_size,
                              hipStream_t stream) {
    const float* x    = (const float*)d_in[0];
    const float* Wt   = (const float*)d_in[1];
    const float* bias = (const float*)d_in[2];
    float* out = (float*)d_out;

    qrnn_mfma<<<dim3(kB * kH), dim3(256), 0, stream>>>(x, Wt, bias, out);
}

// Round 2
// 257.885 us; speedup vs baseline: 1.1117x; 1.0090x over previous
//
#include <hip/hip_runtime.h>
#include <hip/hip_bf16.h>
#include <math.h>

// QRNN3D fused via bf16 MFMA implicit conv-GEMM + in-register fo-pool.
// GEMM per (b,h,t): D[32 gate-ch][128 pix] = sum over 27 taps of
//   A(tap)[32ch x 16c] * B(tap)[16c x 128pix],  A = weights in VGPRs (t-invariant),
//   B = im2col x-slice in LDS.
// C/D layout (32x32x16): col=lane&31=pixel, row=ch=(reg&3)+8*(reg>>2)+4*(lane>>5)
//   => z-gate ch in acc[r], f-gate ch+16 in acc[r+8], same lane: recurrence is
//   per-lane register math; stores coalesced (lane = pixel).
//
// LDS layout THIS REVISION (bank-conflict fix): plane = [kh][c-octet][wpos][8c]
// with 16B cells and an XOR *group* swizzle on the cell index:
//     swz(wp) = (wp & ~7) | ((wp ^ (wp>>3)) & 7)
// - MFMA B-reads: 8-lane clock groups read CONSECUTIVE wp -> consecutive 16B
//   cells -> conflict-free (swz permutes only inside 128B blocks).
// - Staged commits: lanes write wp at stride 4; swz maps {c,c+4,..,c+28} onto
//   all 8 bank groups bijectively -> conflict-free (prev layout was ~16-way).
// Plane stride unchanged: 3 kh x 2 oct x 130 cells x 16B = 12480 B, 4-slot ring.
//
// Software-pipelined staging (T14 split): plane t+2's global loads are ISSUED
// right after the barrier of iter t and COMMITTED to LDS at the start of iter
// t+1 — load latency hides under a full compute phase.
// Slot safety: commit at iter t writes slot (t+1)&3; concurrent compute(t-1)
// reads slots (t-2..t)&3 -> the written slot is the disjoint 4th.

namespace {
constexpr int kB = 4, kC = 16, kT = 31, kH = 128, kW = 128, kHid = 16;
constexpr int kHW  = kH * kW;
constexpr int kTHW = kT * kHW;
constexpr int kCell = 8;             // shorts per cell (8 c bf16 = 16B)
constexpr int kOS  = 130 * kCell;    // c-octet region stride (shorts) = 1040
constexpr int kKS  = 2 * kOS;        // kh-row stride (shorts) = 2080
constexpr int kPS  = 3 * kKS;        // plane stride (shorts) = 6240 (12480 B)
constexpr int kSlots = 4;
}

typedef __attribute__((ext_vector_type(8)))  short  short8;
typedef __attribute__((ext_vector_type(4)))  float  floatv4;
typedef __attribute__((ext_vector_type(16))) float  floatx16;

__device__ __forceinline__ unsigned short f2bf(float f) {
    __hip_bfloat16 h = __float2bfloat16(f);   // RTN
    return __builtin_bit_cast(unsigned short, h);
}

// bank-group swizzle on the wpos cell index (bijective within 8-cell blocks)
__device__ __forceinline__ int swz(int wp) {
    return (wp & ~7) | ((wp ^ (wp >> 3)) & 7);
}

__global__ __launch_bounds__(256, 2) void qrnn_mfma(
    const float* __restrict__ x, const float* __restrict__ Wt,
    const float* __restrict__ bias, float* __restrict__ out)
{
    __shared__ unsigned short lds[kSlots * kPS];   // 49920 B

    // XCD-aware decode: 64 consecutive h per XCD -> staging rows L2-resident.
    const int id  = blockIdx.x;          // 0..511
    const int bh  = (id & 7) * 64 + (id >> 3);
    const int b   = bh >> 7;
    const int h   = bh & (kH - 1);

    const int tid  = threadIdx.x;
    const int lane = tid & 63;
    const int m    = lane & 31;          // A: gate channel ; B/D: pixel-in-tile
    const int hi   = lane >> 5;
    const int chi  = hi * 8;             // k-octet base (c dimension)
    const int n0   = (tid >> 6) * 32;    // wave's pixel tile base

    const float* xb = x + b * (kC * kTHW);

    // ---- A-operand: all 27 tap fragments of W, bf16, in registers ----
    short8 wf[27];
#pragma unroll
    for (int tap = 0; tap < 27; ++tap) {
        short8 v;
#pragma unroll
        for (int j = 0; j < 8; ++j)
            v[j] = (short)f2bf(Wt[m * (kC * 27) + (chi + j) * 27 + tap]);
        wf[tap] = v;
    }

    // ---- per-lane recurrence state, biases, output offsets ----
    float st[8], zb[8], fbv[8];
    int ooff[8];
    const int P = n0 + m;                // this lane's pixel (w coordinate)
#pragma unroll
    for (int r = 0; r < 8; ++r) {
        const int hid = (r & 3) + 8 * (r >> 2) + 4 * hi;   // D-row for reg r
        zb[r]  = bias[hid];
        fbv[r] = bias[kHid + hid];
        st[r]  = 0.0f;
        ooff[r] = ((b * kHid + hid) * kT) * kHW + h * kW + P;
    }

    // ---- B-operand lane base addresses: kw=0/1/2 -> wpos P / P+1 / P+2 ----
    const unsigned short* bK0 = lds + hi * kOS + swz(P)     * kCell;
    const unsigned short* bK1 = lds + hi * kOS + swz(P + 1) * kCell;
    const unsigned short* bK2 = lds + hi * kOS + swz(P + 2) * kCell;

    // ---- pipelined staging: thread = (kh, w-quad, c-octet), 192 active ----
    const bool sact = tid < 192;
    const int  skh  = tid >> 6;          // 0..2 for active threads (wave-uniform)
    const int  swq  = tid & 31;          // w-quad: covers w = swq*4 .. swq*4+3
    const int  soct = (tid >> 5) & 1;    // c-octet 0 or 8
    const int  shr  = h + skh - 1;       // global row this thread stages
    const bool srow = sact && (shr >= 0) && (shr < kH);   // wave-uniform
    const float* sbase = xb + (soct * 8) * kTHW + shr * kW + swq * 4;
    unsigned short* cb0 = lds + skh * kKS + soct * kOS;   // + slot*kPS + swz(wp)*kCell

    int cwoff[4];                        // swizzled commit cell offsets (const idx use)
#pragma unroll
    for (int q = 0; q < 4; ++q) cwoff[q] = swz(swq * 4 + q + 1) * kCell;

    floatv4 sv[8];                       // staged plane: c = soct*8+j, w = quad lane q

    auto sissue = [&](int tp) {          // issue global loads for plane tp (no wait)
#pragma unroll
        for (int j = 0; j < 8; ++j) sv[j] = floatv4{0.f, 0.f, 0.f, 0.f};
        if (srow && (unsigned)tp < (unsigned)kT) {    // wave-uniform branch
            const float* s = sbase + tp * kHW;
#pragma unroll
            for (int j = 0; j < 8; ++j)
                sv[j] = *(const floatv4*)(s + j * kTHW);
        }
    };
    auto scommit = [&](int tp) {         // cvt + write plane tp into its ring slot
        if (sact) {
            unsigned short* pl = cb0 + ((tp + 2 * kSlots) & (kSlots - 1)) * kPS;
#pragma unroll
            for (int q = 0; q < 4; ++q) {
                short8 v;
#pragma unroll
                for (int j = 0; j < 8; ++j) v[j] = (short)f2bf(sv[j][q]);
                *(short8*)(pl + cwoff[q]) = v;
            }
        }
    };

    // ---- halo cells (wpos 0 and 129) of all slots: zero once, never rewritten ----
    if (tid < 48) {   // 4 slots x 3 kh x 2 oct x 2 wp = 48 cells of 16B
        const int s = tid / 12, rem = tid % 12;
        const int khh = rem >> 2, q2 = rem & 3;
        const int oct = q2 >> 1;
        const int wp  = (q2 & 1) * 129;          // swz(0)=0, swz(129)=129
        const short8 z = {0, 0, 0, 0, 0, 0, 0, 0};
        *(short8*)(lds + s * kPS + khh * kKS + oct * kOS + swz(wp) * kCell) = z;
    }

    // ---- prologue: plane -1 (zeros) -> slot 3, plane 0 -> slot 0, plane 1 in regs ----
    sissue(-1); scommit(-1);
    sissue(0);  scommit(0);
    sissue(1);

    for (int t = 0; t < kT; ++t) {
        scommit(t + 1);                  // loads issued a full iteration ago
        __syncthreads();
        sissue(t + 2);                   // in flight across compute(t) + epilogue

        floatx16 acc = {0,0,0,0,0,0,0,0,0,0,0,0,0,0,0,0};
#pragma unroll
        for (int kd = 0; kd < 3; ++kd) {
            const int soff = ((t + kd + 2 * kSlots - 1) & (kSlots - 1)) * kPS;
#pragma unroll
            for (int kh = 0; kh < 3; ++kh) {
                const int o = soff + kh * kKS;
                const short8 b0 = *(const short8*)(bK0 + o);   // kw=0 -> x[P-1]
                const short8 b1 = *(const short8*)(bK1 + o);   // kw=1 -> x[P]
                const short8 b2 = *(const short8*)(bK2 + o);   // kw=2 -> x[P+1]
                acc = __builtin_amdgcn_mfma_f32_32x32x16_bf16(wf[kd*9 + kh*3 + 0], b0, acc, 0, 0, 0);
                acc = __builtin_amdgcn_mfma_f32_32x32x16_bf16(wf[kd*9 + kh*3 + 1], b1, acc, 0, 0, 0);
                acc = __builtin_amdgcn_mfma_f32_32x32x16_bf16(wf[kd*9 + kh*3 + 2], b2, acc, 0, 0, 0);
            }
        }

        // epilogue: gates -> activations -> fo-pool -> coalesced store
#pragma unroll
        for (int r = 0; r < 8; ++r) {
            const float zp = acc[r]     + zb[r];
            const float fp = acc[r + 8] + fbv[r];
            const float e2 = __expf(2.0f * zp);
            const float z  = 1.0f - 2.0f * __builtin_amdgcn_rcpf(e2 + 1.0f);  // tanh(zp)
            const float f  = __builtin_amdgcn_rcpf(1.0f + __expf(-fp));       // sigmoid(fp)
            st[r] = z + f * (st[r] - z);
            out[ooff[r] + t * kHW] = st[r];
        }
    }
}

extern "C" void kernel_launch(void* const* d_in, const int* in_sizes, int n_in,
                              void* d_out, int out_size, void* d_ws, size_t ws_size,
                              hipStream_t stream) {
    const float* x    = (const float*)d_in[0];
    const float* Wt   = (const float*)d_in[1];
    const float* bias = (const float*)d_in[2];
    float* out = (float*)d_out;

    qrnn_mfma<<<dim3(kB * kH), dim3(256), 0, stream>>>(x, Wt, bias, out);
}